// Round 1
// baseline (490.747 us; speedup 1.0000x reference)
//
#include <hip/hip_runtime.h>
#include <hip/hip_bf16.h>
#include <cstdint>
#include <cstddef>

// Dims (fixed by the problem)
#define N_INP 512
#define N_OUT 256
#define H 3
#define HD (H * N_OUT)       // 768
#define AGG_D (H * (N_INP + 1))  // 1539 logical (513 per head: 512 emb + 1 homogeneous)
#define HSTR 522             // per-head stride in bf16 agg (keeps 4B alignment, room for pad)
#define KP 1568              // padded K for MFMA GEMM (multiple of 32; 3*522=1566 <= 1568)

typedef __attribute__((ext_vector_type(8))) short short8;
typedef __attribute__((ext_vector_type(4))) float f32x4;

__device__ inline unsigned short f2bf(float x) {
    union { float f; unsigned u; } v; v.f = x;
    unsigned r = v.u + 0x7fffu + ((v.u >> 16) & 1u);  // RNE
    return (unsigned short)(r >> 16);
}
__device__ inline float bflo2f(unsigned u) {  // low 16 bits -> float
    union { unsigned u; float f; } v; v.u = u << 16; return v.f;
}
__device__ inline float bfhi2f(unsigned u) {  // high 16 bits -> float
    union { unsigned u; float f; } v; v.u = u & 0xffff0000u; return v.f;
}

// async global->LDS, 16B per lane. LDS dest must be the wave-uniform base;
// HW writes lane i at base + i*16.
__device__ inline void glds16(const void* g, void* l) {
    __builtin_amdgcn_global_load_lds(
        (const __attribute__((address_space(1))) void*)g,
        (__attribute__((address_space(3))) void*)l, 16, 0, 0);
}

// ---------------------------------------------------------------------------
// small utility kernels
// ---------------------------------------------------------------------------
__global__ void zero_int_kernel(int* p, int n) {
    int i = blockIdx.x * blockDim.x + threadIdx.x;
    if (i < n) p[i] = 0;
}

// C init: out[i,j] = bz[j]  (gemm split-K atomically accumulates on top)
__global__ void initC_kernel(float* __restrict__ C, const float* __restrict__ bz, int n) {
    int i = blockIdx.x * blockDim.x + threadIdx.x;
    if (i < n) C[i] = bz[i & (N_OUT - 1)];
}

// wave-per-output: v_l[h][o] = sum_t Wsrc[o, h*256+t] * attn_l[h,t]  (v_r: Wdst/attn_r)
__global__ __launch_bounds__(256) void v_kernel(
    const float* __restrict__ Wsrc, const float* __restrict__ Wdst,
    const float* __restrict__ attn_l, const float* __restrict__ attn_r,
    float* __restrict__ v) {
    int wave = threadIdx.x >> 6, lane = threadIdx.x & 63;
    int idx = blockIdx.x * 4 + wave;
    if (idx >= 2 * H * N_INP) return;
    int which = idx / (H * N_INP);
    int r = idx % (H * N_INP);
    int h = r / N_INP, o = r % N_INP;
    const float* W = which ? Wdst : Wsrc;
    const float* at = which ? attn_r : attn_l;
    float s = 0.f;
#pragma unroll
    for (int i = 0; i < N_OUT / 64; ++i) {
        int t = lane + i * 64;
        s += W[(size_t)o * HD + h * N_OUT + t] * at[h * N_OUT + t];
    }
#pragma unroll
    for (int off = 32; off >= 1; off >>= 1) s += __shfl_xor(s, off, 64);
    if (lane == 0) v[idx] = s;
}

// wave-per-output: u (idx<3072) and ebias (idx in [3072,3078))
__global__ __launch_bounds__(256) void u_kernel(
    const float* __restrict__ Wapi, const float* __restrict__ Wfile,
    const float* __restrict__ bapi, const float* __restrict__ bfile,
    const float* __restrict__ v, float* __restrict__ u,
    float* __restrict__ ebias) {
    int wave = threadIdx.x >> 6, lane = threadIdx.x & 63;
    int idx = blockIdx.x * 4 + wave;
    if (idx < 2 * H * N_INP) {
        int which = idx / (H * N_INP);
        int r = idx % (H * N_INP);
        int h = r / N_INP, i = r % N_INP;
        const float* W = which ? Wfile : Wapi;
        const float* vv = v + which * (H * N_INP) + h * N_INP;
        float s = 0.f;
#pragma unroll
        for (int j = 0; j < N_INP / 64; ++j) {
            int o = lane + j * 64;
            s += W[(size_t)i * N_INP + o] * vv[o];
        }
#pragma unroll
        for (int off = 32; off >= 1; off >>= 1) s += __shfl_xor(s, off, 64);
        if (lane == 0) u[idx] = s;
    } else if (idx < 2 * H * N_INP + 6) {
        int k = idx - 2 * H * N_INP;
        int which = k / H, h = k % H;
        const float* b = which ? bfile : bapi;
        const float* vv = v + which * (H * N_INP) + h * N_INP;
        float s = 0.f;
#pragma unroll
        for (int j = 0; j < N_INP / 64; ++j) {
            int o = lane + j * 64;
            s += b[o] * vv[o];
        }
#pragma unroll
        for (int off = 32; off >= 1; off >>= 1) s += __shfl_xor(s, off, 64);
        if (lane == 0) ebias[k] = s;
    }
}

// el[n,h] = emb[n,:] . u[h,:] + ebias[h]   (one wave per node)
// optionally also writes a bf16 copy of emb rows (for the aggregation gather)
__global__ __launch_bounds__(256) void elr_kernel(
    const float* __restrict__ emb, const float* __restrict__ u,
    const float* __restrict__ ebias, float* __restrict__ out,
    unsigned short* __restrict__ embB, int n) {
    __shared__ float su[H * N_INP];
    for (int i = threadIdx.x; i < H * N_INP; i += 256) su[i] = u[i];
    __syncthreads();
    int wave = threadIdx.x >> 6;
    int lane = threadIdx.x & 63;
    int node = blockIdx.x * 4 + wave;
    if (node >= n) return;
    const float4* row = (const float4*)(emb + (size_t)node * N_INP);
    float4 v0 = row[lane];        // cols lane*4 .. +3
    float4 v1 = row[64 + lane];   // cols 256+lane*4 .. +3
    int c0 = lane * 4, c1 = 256 + lane * 4;
    if (embB) {
        unsigned short* o = embB + (size_t)node * N_INP;
        ushort4 p0, p1;
        p0.x = f2bf(v0.x); p0.y = f2bf(v0.y); p0.z = f2bf(v0.z); p0.w = f2bf(v0.w);
        p1.x = f2bf(v1.x); p1.y = f2bf(v1.y); p1.z = f2bf(v1.z); p1.w = f2bf(v1.w);
        *(ushort4*)(o + c0) = p0;
        *(ushort4*)(o + c1) = p1;
    }
    float d[H];
#pragma unroll
    for (int h = 0; h < H; ++h) {
        const float* uh = su + h * N_INP;
        d[h] = v0.x * uh[c0] + v0.y * uh[c0 + 1] + v0.z * uh[c0 + 2] + v0.w * uh[c0 + 3]
             + v1.x * uh[c1] + v1.y * uh[c1 + 1] + v1.z * uh[c1 + 2] + v1.w * uh[c1 + 3];
#pragma unroll
        for (int off = 32; off >= 1; off >>= 1) d[h] += __shfl_xor(d[h], off, 64);
    }
    if (lane == 0) {
#pragma unroll
        for (int h = 0; h < H; ++h) out[(size_t)node * H + h] = d[h] + ebias[h];
    }
}

__global__ void count_kernel(const int* __restrict__ dst, int* __restrict__ counts, int E) {
    int e = blockIdx.x * blockDim.x + threadIdx.x;
    if (e < E) atomicAdd(&counts[dst[e]], 1);
}

// single-block exclusive scan of counts -> offsets, cursor; offsets[n] = total
__global__ __launch_bounds__(1024) void scan_kernel(const int* __restrict__ counts,
                                                    int* __restrict__ offsets,
                                                    int* __restrict__ cursor, int n) {
    __shared__ int part[1024];
    int t = threadIdx.x;
    const int CH = (n + 1023) / 1024;
    int lo = t * CH, hi = min(lo + CH, n);
    int s = 0;
    for (int i = lo; i < hi; ++i) s += counts[i];
    part[t] = s;
    __syncthreads();
    for (int off = 1; off < 1024; off <<= 1) {
        int v = (t >= off) ? part[t - off] : 0;
        __syncthreads();
        part[t] += v;
        __syncthreads();
    }
    int base = (t == 0) ? 0 : part[t - 1];
    for (int i = lo; i < hi; ++i) {
        offsets[i] = base; cursor[i] = base;
        base += counts[i];
    }
    if (t == 1023) offsets[n] = part[1023];
}

__global__ void scatter_kernel(const int* __restrict__ src, const int* __restrict__ dst,
                               int* __restrict__ cursor, int* __restrict__ csr_src, int E) {
    int e = blockIdx.x * blockDim.x + threadIdx.x;
    if (e < E) {
        int slot = atomicAdd(&cursor[dst[e]], 1);
        csr_src[slot] = src[e];
    }
}

// one wave per dst node: edge softmax over its incoming edges (3 heads)
__global__ __launch_bounds__(256) void alpha_kernel(
    const int* __restrict__ offsets, const int* __restrict__ csr_src,
    const float* __restrict__ el, const float* __restrict__ er,
    float* __restrict__ alpha, int nd) {
    int wave = threadIdx.x >> 6;
    int lane = threadIdx.x & 63;
    int d = blockIdx.x * 4 + wave;
    if (d >= nd) return;
    int lo = offsets[d], hi = offsets[d + 1];
    if (lo == hi) return;
    float er0 = er[(size_t)d * H + 0], er1 = er[(size_t)d * H + 1], er2 = er[(size_t)d * H + 2];
    float m0 = -3.4e38f, m1 = -3.4e38f, m2 = -3.4e38f;
    for (int s = lo + lane; s < hi; s += 64) {
        int u = csr_src[s];
        float e0 = el[(size_t)u * H + 0] + er0; e0 = e0 >= 0.f ? e0 : 0.2f * e0;
        float e1 = el[(size_t)u * H + 1] + er1; e1 = e1 >= 0.f ? e1 : 0.2f * e1;
        float e2 = el[(size_t)u * H + 2] + er2; e2 = e2 >= 0.f ? e2 : 0.2f * e2;
        m0 = fmaxf(m0, e0); m1 = fmaxf(m1, e1); m2 = fmaxf(m2, e2);
    }
#pragma unroll
    for (int off = 32; off >= 1; off >>= 1) {
        m0 = fmaxf(m0, __shfl_xor(m0, off, 64));
        m1 = fmaxf(m1, __shfl_xor(m1, off, 64));
        m2 = fmaxf(m2, __shfl_xor(m2, off, 64));
    }
    float s0 = 0.f, s1 = 0.f, s2 = 0.f;
    for (int s = lo + lane; s < hi; s += 64) {
        int u = csr_src[s];
        float e0 = el[(size_t)u * H + 0] + er0; e0 = e0 >= 0.f ? e0 : 0.2f * e0;
        float e1 = el[(size_t)u * H + 1] + er1; e1 = e1 >= 0.f ? e1 : 0.2f * e1;
        float e2 = el[(size_t)u * H + 2] + er2; e2 = e2 >= 0.f ? e2 : 0.2f * e2;
        float a0 = expf(e0 - m0), a1 = expf(e1 - m1), a2 = expf(e2 - m2);
        alpha[(size_t)s * H + 0] = a0; alpha[(size_t)s * H + 1] = a1; alpha[(size_t)s * H + 2] = a2;
        s0 += a0; s1 += a1; s2 += a2;
    }
#pragma unroll
    for (int off = 32; off >= 1; off >>= 1) {
        s0 += __shfl_xor(s0, off, 64);
        s1 += __shfl_xor(s1, off, 64);
        s2 += __shfl_xor(s2, off, 64);
    }
    float i0 = 1.f / s0, i1 = 1.f / s1, i2 = 1.f / s2;
    for (int s = lo + lane; s < hi; s += 64) {
        alpha[(size_t)s * H + 0] *= i0;
        alpha[(size_t)s * H + 1] *= i1;
        alpha[(size_t)s * H + 2] *= i2;
    }
}

// one block (256 threads) per dst: aggB[d, h*HSTR + c] = sum_e alpha[e,h]*embB[src_e, c]
// aggB[d, h*HSTR + 512] = (deg>0) ? 1 : 0 ; cols [513,HSTR) and [3*HSTR,KP) zero pad.
__global__ __launch_bounds__(256) void agg_kernel(
    const int* __restrict__ offsets, const int* __restrict__ csr_src,
    const float* __restrict__ alpha, const unsigned short* __restrict__ embB,
    unsigned short* __restrict__ aggB, int nd) {
    int d = blockIdx.x;
    if (d >= nd) return;
    int tid = threadIdx.x;
    int lo = offsets[d], hi = offsets[d + 1];
    int c = tid * 2;
    float a00 = 0.f, a01 = 0.f, a10 = 0.f, a11 = 0.f, a20 = 0.f, a21 = 0.f;
    for (int s = lo; s < hi; ++s) {
        int u = csr_src[s];
        float w0 = alpha[(size_t)s * H + 0];
        float w1 = alpha[(size_t)s * H + 1];
        float w2 = alpha[(size_t)s * H + 2];
        unsigned v = *(const unsigned*)(embB + (size_t)u * N_INP + c);
        float x = bflo2f(v), y = bfhi2f(v);
        a00 += w0 * x; a01 += w0 * y;
        a10 += w1 * x; a11 += w1 * y;
        a20 += w2 * x; a21 += w2 * y;
    }
    size_t base = (size_t)d * KP;
    *(unsigned*)(aggB + base + 0 * HSTR + c) = (unsigned)f2bf(a00) | ((unsigned)f2bf(a01) << 16);
    *(unsigned*)(aggB + base + 1 * HSTR + c) = (unsigned)f2bf(a10) | ((unsigned)f2bf(a11) << 16);
    *(unsigned*)(aggB + base + 2 * HSTR + c) = (unsigned)f2bf(a20) | ((unsigned)f2bf(a21) << 16);
    if (tid == 0) {
        unsigned short flag = (hi > lo) ? (unsigned short)0x3f80 : (unsigned short)0; // bf16 1.0 / 0.0
#pragma unroll
        for (int h = 0; h < H; ++h) {
            aggB[base + h * HSTR + 512] = flag;
            for (int z = 513; z < HSTR; ++z) aggB[base + h * HSTR + z] = 0;
        }
        aggB[base + 3 * HSTR + 0] = 0;
        aggB[base + 3 * HSTR + 1] = 0;
    }
}

// weight GEMM with MLP + TLP: C[M,256] = A[M,K] @ B[K,256], batched over blockIdx.z.
template <int K>
__global__ __launch_bounds__(256) void wgemm(
    const float* __restrict__ A, int lda, size_t sAz,
    const float* __restrict__ B, int ldb, size_t sBz,
    float* __restrict__ C, int ldc, size_t sCz, int M) {
    A += blockIdx.z * sAz; B += blockIdx.z * sBz; C += blockIdx.z * sCz;
    __shared__ float sA[8 * K];
    __shared__ float red[8 * 256];   // 8 rows x (4 ksub x 64 cols)
    int tid = threadIdx.x;
    int r0 = blockIdx.x * 8;
    int bn = blockIdx.y * 64;
    for (int i = tid; i < 8 * K; i += 256) {
        int r = i / K, k = i % K;
        sA[i] = A[(size_t)(r0 + r) * lda + k];
    }
    __syncthreads();
    int cl = tid & 63, ks = tid >> 6;
    int col = bn + cl;
    const int KC = K / 4;
    float acc[8] = {};
    for (int k0 = ks * KC; k0 < ks * KC + KC; k0 += 8) {
        float b[8];
#pragma unroll
        for (int j = 0; j < 8; ++j) b[j] = B[(size_t)(k0 + j) * ldb + col];
#pragma unroll
        for (int j = 0; j < 8; ++j) {
            float bb = b[j];
#pragma unroll
            for (int i = 0; i < 8; ++i) acc[i] += sA[i * K + k0 + j] * bb;
        }
    }
#pragma unroll
    for (int i = 0; i < 8; ++i) red[i * 256 + ks * 64 + cl] = acc[i];
    __syncthreads();
    for (int t = tid; t < 512; t += 256) {
        int i = t >> 6, c = t & 63;
        float s = red[i * 256 + c] + red[i * 256 + 64 + c]
                + red[i * 256 + 128 + c] + red[i * 256 + 192 + c];
        if (r0 + i < M) C[(size_t)(r0 + i) * ldc + bn + c] = s;
    }
}

// wave-per-output bias rows: idx<768: Mmat[h*513+512, j] = bapi . T_h[:, j]
// idx in [768,1024): bz[j] = gat_bias . Whead[:, j] + bhead[j]
__global__ __launch_bounds__(256) void brow_kernel(
    const float* __restrict__ bapi, const float* __restrict__ T,
    const float* __restrict__ gat_bias, const float* __restrict__ Whead,
    const float* __restrict__ bhead,
    float* __restrict__ Mmat, float* __restrict__ bz) {
    int wave = threadIdx.x >> 6, lane = threadIdx.x & 63;
    int idx = blockIdx.x * 4 + wave;
    if (idx < H * N_OUT) {
        int h = idx / N_OUT, j = idx % N_OUT;
        float s = 0.f;
#pragma unroll
        for (int i = 0; i < N_INP / 64; ++i) {
            int cc = lane + i * 64;
            s += bapi[cc] * T[((size_t)h * N_INP + cc) * N_OUT + j];
        }
#pragma unroll
        for (int off = 32; off >= 1; off >>= 1) s += __shfl_xor(s, off, 64);
        if (lane == 0) Mmat[((size_t)(h * 513 + 512)) * N_OUT + j] = s;
    } else if (idx < H * N_OUT + N_OUT) {
        int j = idx - H * N_OUT;
        float s = 0.f;
#pragma unroll
        for (int i = 0; i < HD / 64; ++i) {
            int f = lane + i * 64;
            s += gat_bias[f] * Whead[(size_t)f * N_OUT + j];
        }
#pragma unroll
        for (int off = 32; off >= 1; off >>= 1) s += __shfl_xor(s, off, 64);
        if (lane == 0) bz[j] = s + bhead[j];
    }
}

// MmatT_bf16[n, k] (K-contiguous, padded): k = h*HSTR + c -> Mmat[h*513+c, n], else 0
__global__ void convT_kernel(const float* __restrict__ Mmat, unsigned short* __restrict__ MmatT) {
    int idx = blockIdx.x * blockDim.x + threadIdx.x;
    if (idx >= N_OUT * KP) return;
    int n = idx / KP, k = idx % KP;
    float v = 0.f;
    if (k < H * HSTR) {
        int h = k / HSTR, c = k % HSTR;
        if (c < 513) v = Mmat[((size_t)(h * 513 + c)) * N_OUT + n];
    }
    MmatT[(size_t)n * KP + k] = f2bf(v);
}

// bf16 MFMA GEMM, split-K x4: C[M,256] += A[M,KP] @ BT[256,KP]^T   (C pre-init'd to bz)
// 128x128 tile, BK=32, 4 waves (2x2 of 64x64). 2-phase async pipeline:
// global_load_lds (16B) double-buffered staging, counted s_waitcnt vmcnt(4),
// raw s_barrier (no vmcnt(0) drain in steady state).
// Grid: (2, 157, 4) = 1256 blocks -> ~4.9 blocks/CU of latency hiding.
__global__ __launch_bounds__(256, 4) void gemm_mfma(
    const unsigned short* __restrict__ A, const unsigned short* __restrict__ BT,
    float* __restrict__ C, int M) {
    __shared__ __align__(16) short As[2][128 * 32];
    __shared__ __align__(16) short Bs[2][128 * 32];
    int tid = threadIdx.x;
    int wave = tid >> 6, lane = tid & 63;
    int bm = blockIdx.y * 128, bn = blockIdx.x * 128;
    int wm = (wave >> 1) * 64, wn = (wave & 1) * 64;
    int quad = lane >> 4, m16 = lane & 15;
    int kz = blockIdx.z;
    int kbeg = kz * 416;                       // 13,13,13,10 k-steps
    int kend = (kz == 3) ? KP : kbeg + 416;

    // staging geometry: wave w, issue p covers rows p*64 + w*16 + (lane>>2);
    // each lane loads 16B at k-chunk (lane&3)*8. LDS dest is the wave-uniform
    // row-block base; HW scatters lane i at base + i*16B == linear [row][32] layout.
    int srow = lane >> 2;
    int schunk = (lane & 3) * 8;

    f32x4 acc[4][4] = {};

    auto stage = [&](int buf, int k0) {
#pragma unroll
        for (int p = 0; p < 2; ++p) {
            int row = p * 64 + wave * 16 + srow;
            int ar = bm + row; if (ar >= M) ar = M - 1;   // clamp: garbage rows masked at epilogue
            glds16(A + (size_t)ar * KP + k0 + schunk, &As[buf][(p * 64 + wave * 16) * 32]);
            glds16(BT + (size_t)(bn + row) * KP + k0 + schunk, &Bs[buf][(p * 64 + wave * 16) * 32]);
        }
    };

    stage(0, kbeg);
    int cur = 0;
    for (int k0 = kbeg; k0 < kend; k0 += 32) {
        if (k0 + 32 < kend) {
            stage(cur ^ 1, k0 + 32);                       // 4 more in flight (8 total)
            asm volatile("s_waitcnt vmcnt(4)" ::: "memory");   // oldest 4 (cur) done
        } else {
            asm volatile("s_waitcnt vmcnt(0)" ::: "memory");   // last tile: drain
        }
        asm volatile("" ::: "memory");
        __builtin_amdgcn_s_barrier();                      // all waves' cur loads landed
        asm volatile("" ::: "memory");
        short8 af[4], bf[4];
#pragma unroll
        for (int t = 0; t < 4; ++t) {
            af[t] = *(const short8*)(&As[cur][(wm + t * 16 + m16) * 32 + quad * 8]);
            bf[t] = *(const short8*)(&Bs[cur][(wn + t * 16 + m16) * 32 + quad * 8]);
        }
#pragma unroll
        for (int mt = 0; mt < 4; ++mt)
#pragma unroll
            for (int nt = 0; nt < 4; ++nt)
                acc[mt][nt] = __builtin_amdgcn_mfma_f32_16x16x32_bf16(
                    af[mt], bf[nt], acc[mt][nt], 0, 0, 0);
        asm volatile("" ::: "memory");
        __builtin_amdgcn_s_barrier();                      // all waves done reading buf[cur]
        asm volatile("" ::: "memory");
        cur ^= 1;
    }
#pragma unroll
    for (int mt = 0; mt < 4; ++mt) {
#pragma unroll
        for (int i = 0; i < 4; ++i) {
            int r = bm + wm + mt * 16 + quad * 4 + i;
            if (r >= M) continue;
#pragma unroll
            for (int nt = 0; nt < 4; ++nt) {
                int col = bn + wn + nt * 16 + m16;
                atomicAdd(&C[(size_t)r * N_OUT + col], acc[mt][nt][i]);
            }
        }
    }
}

// ---------------------------------------------------------------------------
extern "C" void kernel_launch(void* const* d_in, const int* in_sizes, int n_in,
                              void* d_out, int out_size, void* d_ws, size_t ws_size,
                              hipStream_t stream) {
    const float* emb_api  = (const float*)d_in[0];
    const float* emb_file = (const float*)d_in[1];
    // d_in[2] = e_tensor (unused by the reference)
    const int*   src      = (const int*)d_in[3];
    const int*   dst      = (const int*)d_in[4];
    const float* Wapi     = (const float*)d_in[5];
    const float* bapi     = (const float*)d_in[6];
    const float* Wfile    = (const float*)d_in[7];
    const float* bfile    = (const float*)d_in[8];
    const float* Wsrc     = (const float*)d_in[9];
    const float* Wdst     = (const float*)d_in[10];
    const float* attn_l   = (const float*)d_in[11];
    const float* attn_r   = (const float*)d_in[12];
    const float* gat_bias = (const float*)d_in[13];
    const float* Whead    = (const float*)d_in[14];
    const float* bhead    = (const float*)d_in[15];
    float* out = (float*)d_out;

    const int NAPI = in_sizes[0] / N_INP;   // 50000
    const int NFIL = in_sizes[1] / N_INP;   // 20000
    const int E    = in_sizes[3];           // 250000

    // workspace carve-up
    char* p = (char*)d_ws;
    auto alloc = [&](size_t bytes) -> void* {
        void* r = (void*)p;
        p += (bytes + 255) & ~(size_t)255;
        return r;
    };
    float* el      = (float*)alloc((size_t)NAPI * H * 4);
    float* er      = (float*)alloc((size_t)NFIL * H * 4);
    float* vbuf    = (float*)alloc(2 * H * N_INP * 4);
    float* ubuf    = (float*)alloc(2 * H * N_INP * 4);
    float* ebias   = (float*)alloc(8 * 4);
    float* T       = (float*)alloc((size_t)H * N_INP * N_OUT * 4);
    float* Mmat    = (float*)alloc((size_t)AGG_D * N_OUT * 4);
    float* bz      = (float*)alloc(N_OUT * 4);
    int*   counts  = (int*)alloc((size_t)NFIL * 4);
    int*   offsets = (int*)alloc((size_t)(NFIL + 1) * 4);
    int*   cursor  = (int*)alloc((size_t)NFIL * 4);
    int*   csr_src = (int*)alloc((size_t)E * 4);
    float* alphaB  = (float*)alloc((size_t)E * H * 4);
    unsigned short* embB  = (unsigned short*)alloc((size_t)NAPI * N_INP * 2);
    unsigned short* aggB  = (unsigned short*)alloc((size_t)NFIL * KP * 2);
    unsigned short* MmatT = (unsigned short*)alloc((size_t)N_OUT * KP * 2);
    (void)ws_size; (void)n_in; (void)out_size;

    // --- weight precompute (tiny, parallelism-first) ---
    v_kernel<<<(2 * H * N_INP + 3) / 4, 256, 0, stream>>>(Wsrc, Wdst, attn_l, attn_r, vbuf);
    u_kernel<<<(2 * H * N_INP + 6 + 3) / 4, 256, 0, stream>>>(Wapi, Wfile, bapi, bfile, vbuf, ubuf, ebias);
    // T_h = Wsrc[:, h*256:(h+1)*256] @ Whead[h*256:(h+1)*256, :]  (batched over h)
    wgemm<N_OUT><<<dim3(N_INP / 8, 4, H), 256, 0, stream>>>(
        Wsrc, HD, (size_t)N_OUT,
        Whead, N_OUT, (size_t)N_OUT * N_OUT,
        T, N_OUT, (size_t)N_INP * N_OUT, N_INP);
    // Mmat rows [h*513 .. h*513+511] = Wapi @ T_h  (batched over h)
    wgemm<N_INP><<<dim3(N_INP / 8, 4, H), 256, 0, stream>>>(
        Wapi, N_INP, (size_t)0,
        T, N_OUT, (size_t)N_INP * N_OUT,
        Mmat, N_OUT, (size_t)513 * N_OUT, N_INP);
    brow_kernel<<<(H * N_OUT + N_OUT + 3) / 4, 256, 0, stream>>>(
        bapi, T, gat_bias, Whead, bhead, Mmat, bz);
    convT_kernel<<<(N_OUT * KP + 255) / 256, 256, 0, stream>>>(Mmat, MmatT);
    // C = bz (gemm split-K accumulates atomically on top)
    initC_kernel<<<((size_t)NFIL * N_OUT + 255) / 256, 256, 0, stream>>>(out, bz, NFIL * N_OUT);

    // --- attention logits (+ bf16 copy of emb_api) ---
    elr_kernel<<<(NAPI + 3) / 4, 256, 0, stream>>>(emb_api, ubuf, ebias, el, embB, NAPI);
    elr_kernel<<<(NFIL + 3) / 4, 256, 0, stream>>>(emb_file, ubuf + H * N_INP, ebias + 3, er, nullptr, NFIL);

    // --- CSR build (by dst) ---
    zero_int_kernel<<<(NFIL + 255) / 256, 256, 0, stream>>>(counts, NFIL);
    count_kernel<<<(E + 255) / 256, 256, 0, stream>>>(dst, counts, E);
    scan_kernel<<<1, 1024, 0, stream>>>(counts, offsets, cursor, NFIL);
    scatter_kernel<<<(E + 255) / 256, 256, 0, stream>>>(src, dst, cursor, csr_src, E);

    // --- edge softmax + aggregation (bf16 out) ---
    alpha_kernel<<<(NFIL + 3) / 4, 256, 0, stream>>>(offsets, csr_src, el, er, alphaB, NFIL);
    agg_kernel<<<NFIL, 256, 0, stream>>>(offsets, csr_src, alphaB, embB, aggB, NFIL);

    // --- final fused GEMM (bf16 MFMA, split-K x4, atomic accumulate) ---
    gemm_mfma<<<dim3(256 / 128, (NFIL + 127) / 128, 4), 256, 0, stream>>>(
        aggB, MmatT, out, NFIL);
}

// Round 3
// 462.147 us; speedup vs baseline: 1.0619x; 1.0619x over previous
//
#include <hip/hip_runtime.h>
#include <hip/hip_bf16.h>
#include <cstdint>
#include <cstddef>

// Dims (fixed by the problem)
#define N_INP 512
#define N_OUT 256
#define H 3
#define HD (H * N_OUT)       // 768
#define AGG_D (H * (N_INP + 1))  // 1539 logical (513 per head: 512 emb + 1 homogeneous)
#define HSTR 522             // per-head stride in bf16 agg (keeps 4B alignment, room for pad)
#define KP 1568              // padded K for MFMA GEMM (multiple of 32; 3*522=1566 <= 1568)
#define GEMM_NT (KP / 32)    // 49 k-steps

typedef __attribute__((ext_vector_type(8))) short short8;
typedef __attribute__((ext_vector_type(4))) float f32x4;

__device__ inline unsigned short f2bf(float x) {
    union { float f; unsigned u; } v; v.f = x;
    unsigned r = v.u + 0x7fffu + ((v.u >> 16) & 1u);  // RNE
    return (unsigned short)(r >> 16);
}
__device__ inline float bflo2f(unsigned u) {  // low 16 bits -> float
    union { unsigned u; float f; } v; v.u = u << 16; return v.f;
}
__device__ inline float bfhi2f(unsigned u) {  // high 16 bits -> float
    union { unsigned u; float f; } v; v.u = u & 0xffff0000u; return v.f;
}

// ---------------------------------------------------------------------------
// small utility kernels
// ---------------------------------------------------------------------------
__global__ void zero_int_kernel(int* p, int n) {
    int i = blockIdx.x * blockDim.x + threadIdx.x;
    if (i < n) p[i] = 0;
}

// wave-per-output: v_l[h][o] = sum_t Wsrc[o, h*256+t] * attn_l[h,t]  (v_r: Wdst/attn_r)
__global__ __launch_bounds__(256) void v_kernel(
    const float* __restrict__ Wsrc, const float* __restrict__ Wdst,
    const float* __restrict__ attn_l, const float* __restrict__ attn_r,
    float* __restrict__ v) {
    int wave = threadIdx.x >> 6, lane = threadIdx.x & 63;
    int idx = blockIdx.x * 4 + wave;
    if (idx >= 2 * H * N_INP) return;
    int which = idx / (H * N_INP);
    int r = idx % (H * N_INP);
    int h = r / N_INP, o = r % N_INP;
    const float* W = which ? Wdst : Wsrc;
    const float* at = which ? attn_r : attn_l;
    float s = 0.f;
#pragma unroll
    for (int i = 0; i < N_OUT / 64; ++i) {
        int t = lane + i * 64;
        s += W[(size_t)o * HD + h * N_OUT + t] * at[h * N_OUT + t];
    }
#pragma unroll
    for (int off = 32; off >= 1; off >>= 1) s += __shfl_xor(s, off, 64);
    if (lane == 0) v[idx] = s;
}

// wave-per-output: u (idx<3072) and ebias (idx in [3072,3078))
__global__ __launch_bounds__(256) void u_kernel(
    const float* __restrict__ Wapi, const float* __restrict__ Wfile,
    const float* __restrict__ bapi, const float* __restrict__ bfile,
    const float* __restrict__ v, float* __restrict__ u,
    float* __restrict__ ebias) {
    int wave = threadIdx.x >> 6, lane = threadIdx.x & 63;
    int idx = blockIdx.x * 4 + wave;
    if (idx < 2 * H * N_INP) {
        int which = idx / (H * N_INP);
        int r = idx % (H * N_INP);
        int h = r / N_INP, i = r % N_INP;
        const float* W = which ? Wfile : Wapi;
        const float* vv = v + which * (H * N_INP) + h * N_INP;
        float s = 0.f;
#pragma unroll
        for (int j = 0; j < N_INP / 64; ++j) {
            int o = lane + j * 64;
            s += W[(size_t)i * N_INP + o] * vv[o];
        }
#pragma unroll
        for (int off = 32; off >= 1; off >>= 1) s += __shfl_xor(s, off, 64);
        if (lane == 0) u[idx] = s;
    } else if (idx < 2 * H * N_INP + 6) {
        int k = idx - 2 * H * N_INP;
        int which = k / H, h = k % H;
        const float* b = which ? bfile : bapi;
        const float* vv = v + which * (H * N_INP) + h * N_INP;
        float s = 0.f;
#pragma unroll
        for (int j = 0; j < N_INP / 64; ++j) {
            int o = lane + j * 64;
            s += b[o] * vv[o];
        }
#pragma unroll
        for (int off = 32; off >= 1; off >>= 1) s += __shfl_xor(s, off, 64);
        if (lane == 0) ebias[k] = s;
    }
}

// el[n,h] = emb[n,:] . u[h,:] + ebias[h]   (one wave per node)
// optionally also writes a bf16 copy of emb rows (for the aggregation gather)
__global__ __launch_bounds__(256) void elr_kernel(
    const float* __restrict__ emb, const float* __restrict__ u,
    const float* __restrict__ ebias, float* __restrict__ out,
    unsigned short* __restrict__ embB, int n) {
    __shared__ float su[H * N_INP];
    for (int i = threadIdx.x; i < H * N_INP; i += 256) su[i] = u[i];
    __syncthreads();
    int wave = threadIdx.x >> 6;
    int lane = threadIdx.x & 63;
    int node = blockIdx.x * 4 + wave;
    if (node >= n) return;
    const float4* row = (const float4*)(emb + (size_t)node * N_INP);
    float4 v0 = row[lane];        // cols lane*4 .. +3
    float4 v1 = row[64 + lane];   // cols 256+lane*4 .. +3
    int c0 = lane * 4, c1 = 256 + lane * 4;
    if (embB) {
        unsigned short* o = embB + (size_t)node * N_INP;
        ushort4 p0, p1;
        p0.x = f2bf(v0.x); p0.y = f2bf(v0.y); p0.z = f2bf(v0.z); p0.w = f2bf(v0.w);
        p1.x = f2bf(v1.x); p1.y = f2bf(v1.y); p1.z = f2bf(v1.z); p1.w = f2bf(v1.w);
        *(ushort4*)(o + c0) = p0;
        *(ushort4*)(o + c1) = p1;
    }
    float d[H];
#pragma unroll
    for (int h = 0; h < H; ++h) {
        const float* uh = su + h * N_INP;
        d[h] = v0.x * uh[c0] + v0.y * uh[c0 + 1] + v0.z * uh[c0 + 2] + v0.w * uh[c0 + 3]
             + v1.x * uh[c1] + v1.y * uh[c1 + 1] + v1.z * uh[c1 + 2] + v1.w * uh[c1 + 3];
#pragma unroll
        for (int off = 32; off >= 1; off >>= 1) d[h] += __shfl_xor(d[h], off, 64);
    }
    if (lane == 0) {
#pragma unroll
        for (int h = 0; h < H; ++h) out[(size_t)node * H + h] = d[h] + ebias[h];
    }
}

__global__ void count_kernel(const int* __restrict__ dst, int* __restrict__ counts, int E) {
    int e = blockIdx.x * blockDim.x + threadIdx.x;
    if (e < E) atomicAdd(&counts[dst[e]], 1);
}

// single-block exclusive scan of counts -> offsets, cursor; offsets[n] = total
__global__ __launch_bounds__(1024) void scan_kernel(const int* __restrict__ counts,
                                                    int* __restrict__ offsets,
                                                    int* __restrict__ cursor, int n) {
    __shared__ int part[1024];
    int t = threadIdx.x;
    const int CH = (n + 1023) / 1024;
    int lo = t * CH, hi = min(lo + CH, n);
    int s = 0;
    for (int i = lo; i < hi; ++i) s += counts[i];
    part[t] = s;
    __syncthreads();
    for (int off = 1; off < 1024; off <<= 1) {
        int v = (t >= off) ? part[t - off] : 0;
        __syncthreads();
        part[t] += v;
        __syncthreads();
    }
    int base = (t == 0) ? 0 : part[t - 1];
    for (int i = lo; i < hi; ++i) {
        offsets[i] = base; cursor[i] = base;
        base += counts[i];
    }
    if (t == 1023) offsets[n] = part[1023];
}

__global__ void scatter_kernel(const int* __restrict__ src, const int* __restrict__ dst,
                               int* __restrict__ cursor, int* __restrict__ csr_src, int E) {
    int e = blockIdx.x * blockDim.x + threadIdx.x;
    if (e < E) {
        int slot = atomicAdd(&cursor[dst[e]], 1);
        csr_src[slot] = src[e];
    }
}

// one wave per dst node: edge softmax over its incoming edges (3 heads)
__global__ __launch_bounds__(256) void alpha_kernel(
    const int* __restrict__ offsets, const int* __restrict__ csr_src,
    const float* __restrict__ el, const float* __restrict__ er,
    float* __restrict__ alpha, int nd) {
    int wave = threadIdx.x >> 6;
    int lane = threadIdx.x & 63;
    int d = blockIdx.x * 4 + wave;
    if (d >= nd) return;
    int lo = offsets[d], hi = offsets[d + 1];
    if (lo == hi) return;
    float er0 = er[(size_t)d * H + 0], er1 = er[(size_t)d * H + 1], er2 = er[(size_t)d * H + 2];
    float m0 = -3.4e38f, m1 = -3.4e38f, m2 = -3.4e38f;
    for (int s = lo + lane; s < hi; s += 64) {
        int u = csr_src[s];
        float e0 = el[(size_t)u * H + 0] + er0; e0 = e0 >= 0.f ? e0 : 0.2f * e0;
        float e1 = el[(size_t)u * H + 1] + er1; e1 = e1 >= 0.f ? e1 : 0.2f * e1;
        float e2 = el[(size_t)u * H + 2] + er2; e2 = e2 >= 0.f ? e2 : 0.2f * e2;
        m0 = fmaxf(m0, e0); m1 = fmaxf(m1, e1); m2 = fmaxf(m2, e2);
    }
#pragma unroll
    for (int off = 32; off >= 1; off >>= 1) {
        m0 = fmaxf(m0, __shfl_xor(m0, off, 64));
        m1 = fmaxf(m1, __shfl_xor(m1, off, 64));
        m2 = fmaxf(m2, __shfl_xor(m2, off, 64));
    }
    float s0 = 0.f, s1 = 0.f, s2 = 0.f;
    for (int s = lo + lane; s < hi; s += 64) {
        int u = csr_src[s];
        float e0 = el[(size_t)u * H + 0] + er0; e0 = e0 >= 0.f ? e0 : 0.2f * e0;
        float e1 = el[(size_t)u * H + 1] + er1; e1 = e1 >= 0.f ? e1 : 0.2f * e1;
        float e2 = el[(size_t)u * H + 2] + er2; e2 = e2 >= 0.f ? e2 : 0.2f * e2;
        float a0 = expf(e0 - m0), a1 = expf(e1 - m1), a2 = expf(e2 - m2);
        alpha[(size_t)s * H + 0] = a0; alpha[(size_t)s * H + 1] = a1; alpha[(size_t)s * H + 2] = a2;
        s0 += a0; s1 += a1; s2 += a2;
    }
#pragma unroll
    for (int off = 32; off >= 1; off >>= 1) {
        s0 += __shfl_xor(s0, off, 64);
        s1 += __shfl_xor(s1, off, 64);
        s2 += __shfl_xor(s2, off, 64);
    }
    float i0 = 1.f / s0, i1 = 1.f / s1, i2 = 1.f / s2;
    for (int s = lo + lane; s < hi; s += 64) {
        alpha[(size_t)s * H + 0] *= i0;
        alpha[(size_t)s * H + 1] *= i1;
        alpha[(size_t)s * H + 2] *= i2;
    }
}

// one block (256 threads) per dst: aggB[d, h*HSTR + c] = sum_e alpha[e,h]*embB[src_e, c]
// aggB[d, h*HSTR + 512] = (deg>0) ? 1 : 0 ; cols [513,HSTR) and [3*HSTR,KP) zero pad.
__global__ __launch_bounds__(256) void agg_kernel(
    const int* __restrict__ offsets, const int* __restrict__ csr_src,
    const float* __restrict__ alpha, const unsigned short* __restrict__ embB,
    unsigned short* __restrict__ aggB, int nd) {
    int d = blockIdx.x;
    if (d >= nd) return;
    int tid = threadIdx.x;
    int lo = offsets[d], hi = offsets[d + 1];
    int c = tid * 2;
    float a00 = 0.f, a01 = 0.f, a10 = 0.f, a11 = 0.f, a20 = 0.f, a21 = 0.f;
    for (int s = lo; s < hi; ++s) {
        int u = csr_src[s];
        float w0 = alpha[(size_t)s * H + 0];
        float w1 = alpha[(size_t)s * H + 1];
        float w2 = alpha[(size_t)s * H + 2];
        unsigned v = *(const unsigned*)(embB + (size_t)u * N_INP + c);
        float x = bflo2f(v), y = bfhi2f(v);
        a00 += w0 * x; a01 += w0 * y;
        a10 += w1 * x; a11 += w1 * y;
        a20 += w2 * x; a21 += w2 * y;
    }
    size_t base = (size_t)d * KP;
    *(unsigned*)(aggB + base + 0 * HSTR + c) = (unsigned)f2bf(a00) | ((unsigned)f2bf(a01) << 16);
    *(unsigned*)(aggB + base + 1 * HSTR + c) = (unsigned)f2bf(a10) | ((unsigned)f2bf(a11) << 16);
    *(unsigned*)(aggB + base + 2 * HSTR + c) = (unsigned)f2bf(a20) | ((unsigned)f2bf(a21) << 16);
    if (tid == 0) {
        unsigned short flag = (hi > lo) ? (unsigned short)0x3f80 : (unsigned short)0; // bf16 1.0 / 0.0
#pragma unroll
        for (int h = 0; h < H; ++h) {
            aggB[base + h * HSTR + 512] = flag;
            for (int z = 513; z < HSTR; ++z) aggB[base + h * HSTR + z] = 0;
        }
        aggB[base + 3 * HSTR + 0] = 0;
        aggB[base + 3 * HSTR + 1] = 0;
    }
}

// weight GEMM with MLP + TLP: C[M,256] = A[M,K] @ B[K,256], batched over blockIdx.z.
template <int K>
__global__ __launch_bounds__(256) void wgemm(
    const float* __restrict__ A, int lda, size_t sAz,
    const float* __restrict__ B, int ldb, size_t sBz,
    float* __restrict__ C, int ldc, size_t sCz, int M) {
    A += blockIdx.z * sAz; B += blockIdx.z * sBz; C += blockIdx.z * sCz;
    __shared__ float sA[8 * K];
    __shared__ float red[8 * 256];   // 8 rows x (4 ksub x 64 cols)
    int tid = threadIdx.x;
    int r0 = blockIdx.x * 8;
    int bn = blockIdx.y * 64;
    for (int i = tid; i < 8 * K; i += 256) {
        int r = i / K, k = i % K;
        sA[i] = A[(size_t)(r0 + r) * lda + k];
    }
    __syncthreads();
    int cl = tid & 63, ks = tid >> 6;
    int col = bn + cl;
    const int KC = K / 4;
    float acc[8] = {};
    for (int k0 = ks * KC; k0 < ks * KC + KC; k0 += 8) {
        float b[8];
#pragma unroll
        for (int j = 0; j < 8; ++j) b[j] = B[(size_t)(k0 + j) * ldb + col];
#pragma unroll
        for (int j = 0; j < 8; ++j) {
            float bb = b[j];
#pragma unroll
            for (int i = 0; i < 8; ++i) acc[i] += sA[i * K + k0 + j] * bb;
        }
    }
#pragma unroll
    for (int i = 0; i < 8; ++i) red[i * 256 + ks * 64 + cl] = acc[i];
    __syncthreads();
    for (int t = tid; t < 512; t += 256) {
        int i = t >> 6, c = t & 63;
        float s = red[i * 256 + c] + red[i * 256 + 64 + c]
                + red[i * 256 + 128 + c] + red[i * 256 + 192 + c];
        if (r0 + i < M) C[(size_t)(r0 + i) * ldc + bn + c] = s;
    }
}

// wave-per-output bias rows: idx<768: Mmat[h*513+512, j] = bapi . T_h[:, j]
// idx in [768,1024): bz[j] = gat_bias . Whead[:, j] + bhead[j]
__global__ __launch_bounds__(256) void brow_kernel(
    const float* __restrict__ bapi, const float* __restrict__ T,
    const float* __restrict__ gat_bias, const float* __restrict__ Whead,
    const float* __restrict__ bhead,
    float* __restrict__ Mmat, float* __restrict__ bz) {
    int wave = threadIdx.x >> 6, lane = threadIdx.x & 63;
    int idx = blockIdx.x * 4 + wave;
    if (idx < H * N_OUT) {
        int h = idx / N_OUT, j = idx % N_OUT;
        float s = 0.f;
#pragma unroll
        for (int i = 0; i < N_INP / 64; ++i) {
            int cc = lane + i * 64;
            s += bapi[cc] * T[((size_t)h * N_INP + cc) * N_OUT + j];
        }
#pragma unroll
        for (int off = 32; off >= 1; off >>= 1) s += __shfl_xor(s, off, 64);
        if (lane == 0) Mmat[((size_t)(h * 513 + 512)) * N_OUT + j] = s;
    } else if (idx < H * N_OUT + N_OUT) {
        int j = idx - H * N_OUT;
        float s = 0.f;
#pragma unroll
        for (int i = 0; i < HD / 64; ++i) {
            int f = lane + i * 64;
            s += gat_bias[f] * Whead[(size_t)f * N_OUT + j];
        }
#pragma unroll
        for (int off = 32; off >= 1; off >>= 1) s += __shfl_xor(s, off, 64);
        if (lane == 0) bz[j] = s + bhead[j];
    }
}

// MmatT_bf16[n, k] (K-contiguous, padded): k = h*HSTR + c -> Mmat[h*513+c, n], else 0
__global__ void convT_kernel(const float* __restrict__ Mmat, unsigned short* __restrict__ MmatT) {
    int idx = blockIdx.x * blockDim.x + threadIdx.x;
    if (idx >= N_OUT * KP) return;
    int n = idx / KP, k = idx % KP;
    float v = 0.f;
    if (k < H * HSTR) {
        int h = k / HSTR, c = k % HSTR;
        if (c < 513) v = Mmat[((size_t)(h * 513 + c)) * N_OUT + n];
    }
    MmatT[(size_t)n * KP + k] = f2bf(v);
}

// bf16 MFMA GEMM: C[M,256] = A[M,KP] @ BT[256,KP]^T + bias
// BM=32, BN=256 (full N): A streamed from HBM exactly once, B (0.8 MB) L2-resident.
// Reg-staged double-buffer: global->VGPR loads for tile t+3 issued at iter t,
// ds_write at t+1's slot (compiler emits counted vmcnt for the reg deps ->
// ~2 iters of latency cover), raw s_barrier + lgkmcnt(0) only (no vmcnt drain,
// no atomics). 4 waves: each computes 32 rows x 64 cols (acc[2][4]).
// Grid: M/32 = 625 blocks, LDS 36 KB -> 4 blocks/CU.
__global__ __launch_bounds__(256) void gemm_mfma(
    const unsigned short* __restrict__ A, const unsigned short* __restrict__ BT,
    const float* __restrict__ bias, float* __restrict__ C, int M) {
    __shared__ __align__(16) short As[2][32 * 32];    // 2 x 2 KB
    __shared__ __align__(16) short Bs[2][256 * 32];   // 2 x 16 KB
    int tid = threadIdx.x;
    int wave = tid >> 6, lane = tid & 63;
    int bm = blockIdx.x * 32;
    int wn = wave * 64;
    int quad = lane >> 4, m16 = lane & 15;

    // staging geometry: srow = tid>>2 (0..63), schunk = 16B column group
    int srow = tid >> 2;
    int schunk = (tid & 3) * 8;           // in shorts
    bool doA = (tid < 128);               // waves 0,1 also stage the 32-row A tile
    int arow_l = doA ? srow : 0;          // 0..31
    int arow = bm + arow_l; if (arow >= M) arow = M - 1;
    const unsigned short* Ap  = A + (size_t)arow * KP + schunk;
    const unsigned short* Bp0 = BT + (size_t)(srow      ) * KP + schunk;
    const unsigned short* Bp1 = BT + (size_t)(srow +  64) * KP + schunk;
    const unsigned short* Bp2 = BT + (size_t)(srow + 128) * KP + schunk;
    const unsigned short* Bp3 = BT + (size_t)(srow + 192) * KP + schunk;

    f32x4 acc[2][4] = {};
    short8 a0{}, b00{}, b01{}, b02{}, b03{};   // reg set 0 (even tiles)
    short8 a1{}, b10{}, b11{}, b12{}, b13{};   // reg set 1 (odd tiles)

    auto LD = [&](short8& ra, short8& r0, short8& r1, short8& r2, short8& r3, int k0) {
        if (doA) ra = *(const short8*)(Ap + k0);
        r0 = *(const short8*)(Bp0 + k0);
        r1 = *(const short8*)(Bp1 + k0);
        r2 = *(const short8*)(Bp2 + k0);
        r3 = *(const short8*)(Bp3 + k0);
    };
    auto WR = [&](int buf, short8 ra, short8 r0, short8 r1, short8 r2, short8 r3) {
        if (doA) *(short8*)(&As[buf][arow_l * 32 + schunk]) = ra;
        *(short8*)(&Bs[buf][(srow      ) * 32 + schunk]) = r0;
        *(short8*)(&Bs[buf][(srow +  64) * 32 + schunk]) = r1;
        *(short8*)(&Bs[buf][(srow + 128) * 32 + schunk]) = r2;
        *(short8*)(&Bs[buf][(srow + 192) * 32 + schunk]) = r3;
    };
    auto FENCE = [&]() {
        asm volatile("s_waitcnt lgkmcnt(0)" ::: "memory");
        __builtin_amdgcn_sched_barrier(0);
        __builtin_amdgcn_s_barrier();
        __builtin_amdgcn_sched_barrier(0);
    };

    // prologue: tiles 0,1 loaded; tile 0 written; tile 2 in flight (set 0)
    LD(a0, b00, b01, b02, b03, 0);
    LD(a1, b10, b11, b12, b13, 32);
    WR(0, a0, b00, b01, b02, b03);
    LD(a0, b00, b01, b02, b03, 64);
    FENCE();

    for (int t = 0; t < GEMM_NT; ++t) {
        int rb = t & 1;
        short8 af[2], bf[4];
#pragma unroll
        for (int mt = 0; mt < 2; ++mt)
            af[mt] = *(const short8*)(&As[rb][(mt * 16 + m16) * 32 + quad * 8]);
#pragma unroll
        for (int nt = 0; nt < 4; ++nt)
            bf[nt] = *(const short8*)(&Bs[rb][(wn + nt * 16 + m16) * 32 + quad * 8]);
        // write tile t+1 (held in set (t+1)&1), then refill that set with tile t+3
        int k3 = (t + 3) * 32;
        if (t & 1) {   // t odd -> tile t+1 even -> set 0
            if (t + 1 < GEMM_NT) WR(rb ^ 1, a0, b00, b01, b02, b03);
            if (t + 3 < GEMM_NT) LD(a0, b00, b01, b02, b03, k3);
        } else {       // t even -> tile t+1 odd -> set 1
            if (t + 1 < GEMM_NT) WR(rb ^ 1, a1, b10, b11, b12, b13);
            if (t + 3 < GEMM_NT) LD(a1, b10, b11, b12, b13, k3);
        }
#pragma unroll
        for (int mt = 0; mt < 2; ++mt)
#pragma unroll
            for (int nt = 0; nt < 4; ++nt)
                acc[mt][nt] = __builtin_amdgcn_mfma_f32_16x16x32_bf16(
                    af[mt], bf[nt], acc[mt][nt], 0, 0, 0);
        FENCE();
    }

    float bcol[4];
#pragma unroll
    for (int nt = 0; nt < 4; ++nt) bcol[nt] = bias[wn + nt * 16 + m16];
#pragma unroll
    for (int mt = 0; mt < 2; ++mt) {
#pragma unroll
        for (int i = 0; i < 4; ++i) {
            int r = bm + mt * 16 + quad * 4 + i;
            if (r >= M) continue;
#pragma unroll
            for (int nt = 0; nt < 4; ++nt) {
                int col = wn + nt * 16 + m16;
                C[(size_t)r * N_OUT + col] = acc[mt][nt][i] + bcol[nt];
            }
        }
    }
}

// ---------------------------------------------------------------------------
extern "C" void kernel_launch(void* const* d_in, const int* in_sizes, int n_in,
                              void* d_out, int out_size, void* d_ws, size_t ws_size,
                              hipStream_t stream) {
    const float* emb_api  = (const float*)d_in[0];
    const float* emb_file = (const float*)d_in[1];
    // d_in[2] = e_tensor (unused by the reference)
    const int*   src      = (const int*)d_in[3];
    const int*   dst      = (const int*)d_in[4];
    const float* Wapi     = (const float*)d_in[5];
    const float* bapi     = (const float*)d_in[6];
    const float* Wfile    = (const float*)d_in[7];
    const float* bfile    = (const float*)d_in[8];
    const float* Wsrc     = (const float*)d_in[9];
    const float* Wdst     = (const float*)d_in[10];
    const float* attn_l   = (const float*)d_in[11];
    const float* attn_r   = (const float*)d_in[12];
    const float* gat_bias = (const float*)d_in[13];
    const float* Whead    = (const float*)d_in[14];
    const float* bhead    = (const float*)d_in[15];
    float* out = (float*)d_out;

    const int NAPI = in_sizes[0] / N_INP;   // 50000
    const int NFIL = in_sizes[1] / N_INP;   // 20000
    const int E    = in_sizes[3];           // 250000

    // workspace carve-up
    char* p = (char*)d_ws;
    auto alloc = [&](size_t bytes) -> void* {
        void* r = (void*)p;
        p += (bytes + 255) & ~(size_t)255;
        return r;
    };
    float* el      = (float*)alloc((size_t)NAPI * H * 4);
    float* er      = (float*)alloc((size_t)NFIL * H * 4);
    float* vbuf    = (float*)alloc(2 * H * N_INP * 4);
    float* ubuf    = (float*)alloc(2 * H * N_INP * 4);
    float* ebias   = (float*)alloc(8 * 4);
    float* T       = (float*)alloc((size_t)H * N_INP * N_OUT * 4);
    float* Mmat    = (float*)alloc((size_t)AGG_D * N_OUT * 4);
    float* bz      = (float*)alloc(N_OUT * 4);
    int*   counts  = (int*)alloc((size_t)NFIL * 4);
    int*   offsets = (int*)alloc((size_t)(NFIL + 1) * 4);
    int*   cursor  = (int*)alloc((size_t)NFIL * 4);
    int*   csr_src = (int*)alloc((size_t)E * 4);
    float* alphaB  = (float*)alloc((size_t)E * H * 4);
    unsigned short* embB  = (unsigned short*)alloc((size_t)NAPI * N_INP * 2);
    unsigned short* aggB  = (unsigned short*)alloc((size_t)NFIL * KP * 2);
    unsigned short* MmatT = (unsigned short*)alloc((size_t)N_OUT * KP * 2);
    (void)ws_size; (void)n_in; (void)out_size;

    // --- weight precompute (tiny, parallelism-first) ---
    v_kernel<<<(2 * H * N_INP + 3) / 4, 256, 0, stream>>>(Wsrc, Wdst, attn_l, attn_r, vbuf);
    u_kernel<<<(2 * H * N_INP + 6 + 3) / 4, 256, 0, stream>>>(Wapi, Wfile, bapi, bfile, vbuf, ubuf, ebias);
    // T_h = Wsrc[:, h*256:(h+1)*256] @ Whead[h*256:(h+1)*256, :]  (batched over h)
    wgemm<N_OUT><<<dim3(N_INP / 8, 4, H), 256, 0, stream>>>(
        Wsrc, HD, (size_t)N_OUT,
        Whead, N_OUT, (size_t)N_OUT * N_OUT,
        T, N_OUT, (size_t)N_INP * N_OUT, N_INP);
    // Mmat rows [h*513 .. h*513+511] = Wapi @ T_h  (batched over h)
    wgemm<N_INP><<<dim3(N_INP / 8, 4, H), 256, 0, stream>>>(
        Wapi, N_INP, (size_t)0,
        T, N_OUT, (size_t)N_INP * N_OUT,
        Mmat, N_OUT, (size_t)513 * N_OUT, N_INP);
    brow_kernel<<<(H * N_OUT + N_OUT + 3) / 4, 256, 0, stream>>>(
        bapi, T, gat_bias, Whead, bhead, Mmat, bz);
    convT_kernel<<<(N_OUT * KP + 255) / 256, 256, 0, stream>>>(Mmat, MmatT);

    // --- attention logits (+ bf16 copy of emb_api) ---
    elr_kernel<<<(NAPI + 3) / 4, 256, 0, stream>>>(emb_api, ubuf, ebias, el, embB, NAPI);
    elr_kernel<<<(NFIL + 3) / 4, 256, 0, stream>>>(emb_file, ubuf + H * N_INP, ebias + 3, er, nullptr, NFIL);

    // --- CSR build (by dst) ---
    zero_int_kernel<<<(NFIL + 255) / 256, 256, 0, stream>>>(counts, NFIL);
    count_kernel<<<(E + 255) / 256, 256, 0, stream>>>(dst, counts, E);
    scan_kernel<<<1, 1024, 0, stream>>>(counts, offsets, cursor, NFIL);
    scatter_kernel<<<(E + 255) / 256, 256, 0, stream>>>(src, dst, cursor, csr_src, E);

    // --- edge softmax + aggregation (bf16 out) ---
    alpha_kernel<<<(NFIL + 3) / 4, 256, 0, stream>>>(offsets, csr_src, el, er, alphaB, NFIL);
    agg_kernel<<<NFIL, 256, 0, stream>>>(offsets, csr_src, alphaB, embB, aggB, NFIL);

    // --- final fused GEMM (bf16 MFMA): out = aggB @ MmatT^T + bz ---
    gemm_mfma<<<dim3((NFIL + 31) / 32), 256, 0, stream>>>(
        aggB, MmatT, bz, out, NFIL);
}

// Round 4
// 436.046 us; speedup vs baseline: 1.1254x; 1.0599x over previous
//
#include <hip/hip_runtime.h>
#include <hip/hip_bf16.h>
#include <cstdint>
#include <cstddef>

// Dims (fixed by the problem)
#define N_INP 512
#define N_OUT 256
#define H 3
#define HD (H * N_OUT)       // 768
#define AGG_D (H * (N_INP + 1))  // 1539 logical (513 per head: 512 emb + 1 homogeneous)
#define HSTR 522             // per-head stride in bf16 agg (keeps 4B alignment, room for pad)
#define KP 1568              // padded K for MFMA GEMM (multiple of 32; 3*522=1566 <= 1568)
#define GEMM_NT (KP / 32)    // 49 k-steps

typedef __attribute__((ext_vector_type(8))) short short8;
typedef __attribute__((ext_vector_type(4))) float f32x4;

__device__ inline unsigned short f2bf(float x) {
    union { float f; unsigned u; } v; v.f = x;
    unsigned r = v.u + 0x7fffu + ((v.u >> 16) & 1u);  // RNE
    return (unsigned short)(r >> 16);
}
__device__ inline float bflo2f(unsigned u) {  // low 16 bits -> float
    union { unsigned u; float f; } v; v.u = u << 16; return v.f;
}
__device__ inline float bfhi2f(unsigned u) {  // high 16 bits -> float
    union { unsigned u; float f; } v; v.u = u & 0xffff0000u; return v.f;
}

// ---------------------------------------------------------------------------
// small utility kernels
// ---------------------------------------------------------------------------
__global__ void zero_int_kernel(int* p, int n) {
    int i = blockIdx.x * blockDim.x + threadIdx.x;
    if (i < n) p[i] = 0;
}

// wave-per-output: v_l[h][o] = sum_t Wsrc[o, h*256+t] * attn_l[h,t]  (v_r: Wdst/attn_r)
__global__ __launch_bounds__(256) void v_kernel(
    const float* __restrict__ Wsrc, const float* __restrict__ Wdst,
    const float* __restrict__ attn_l, const float* __restrict__ attn_r,
    float* __restrict__ v) {
    int wave = threadIdx.x >> 6, lane = threadIdx.x & 63;
    int idx = blockIdx.x * 4 + wave;
    if (idx >= 2 * H * N_INP) return;
    int which = idx / (H * N_INP);
    int r = idx % (H * N_INP);
    int h = r / N_INP, o = r % N_INP;
    const float* W = which ? Wdst : Wsrc;
    const float* at = which ? attn_r : attn_l;
    float s = 0.f;
#pragma unroll
    for (int i = 0; i < N_OUT / 64; ++i) {
        int t = lane + i * 64;
        s += W[(size_t)o * HD + h * N_OUT + t] * at[h * N_OUT + t];
    }
#pragma unroll
    for (int off = 32; off >= 1; off >>= 1) s += __shfl_xor(s, off, 64);
    if (lane == 0) v[idx] = s;
}

// wave-per-output: u (idx<3072) and ebias (idx in [3072,3078))
__global__ __launch_bounds__(256) void u_kernel(
    const float* __restrict__ Wapi, const float* __restrict__ Wfile,
    const float* __restrict__ bapi, const float* __restrict__ bfile,
    const float* __restrict__ v, float* __restrict__ u,
    float* __restrict__ ebias) {
    int wave = threadIdx.x >> 6, lane = threadIdx.x & 63;
    int idx = blockIdx.x * 4 + wave;
    if (idx < 2 * H * N_INP) {
        int which = idx / (H * N_INP);
        int r = idx % (H * N_INP);
        int h = r / N_INP, i = r % N_INP;
        const float* W = which ? Wfile : Wapi;
        const float* vv = v + which * (H * N_INP) + h * N_INP;
        float s = 0.f;
#pragma unroll
        for (int j = 0; j < N_INP / 64; ++j) {
            int o = lane + j * 64;
            s += W[(size_t)i * N_INP + o] * vv[o];
        }
#pragma unroll
        for (int off = 32; off >= 1; off >>= 1) s += __shfl_xor(s, off, 64);
        if (lane == 0) u[idx] = s;
    } else if (idx < 2 * H * N_INP + 6) {
        int k = idx - 2 * H * N_INP;
        int which = k / H, h = k % H;
        const float* b = which ? bfile : bapi;
        const float* vv = v + which * (H * N_INP) + h * N_INP;
        float s = 0.f;
#pragma unroll
        for (int j = 0; j < N_INP / 64; ++j) {
            int o = lane + j * 64;
            s += b[o] * vv[o];
        }
#pragma unroll
        for (int off = 32; off >= 1; off >>= 1) s += __shfl_xor(s, off, 64);
        if (lane == 0) ebias[k] = s;
    }
}

// el[n,h] = emb[n,:] . u[h,:] + ebias[h]   (one wave per node)
// optionally also writes a bf16 copy of emb rows (for the aggregation gather)
__global__ __launch_bounds__(256) void elr_kernel(
    const float* __restrict__ emb, const float* __restrict__ u,
    const float* __restrict__ ebias, float* __restrict__ out,
    unsigned short* __restrict__ embB, int n) {
    __shared__ float su[H * N_INP];
    for (int i = threadIdx.x; i < H * N_INP; i += 256) su[i] = u[i];
    __syncthreads();
    int wave = threadIdx.x >> 6;
    int lane = threadIdx.x & 63;
    int node = blockIdx.x * 4 + wave;
    if (node >= n) return;
    const float4* row = (const float4*)(emb + (size_t)node * N_INP);
    float4 v0 = row[lane];        // cols lane*4 .. +3
    float4 v1 = row[64 + lane];   // cols 256+lane*4 .. +3
    int c0 = lane * 4, c1 = 256 + lane * 4;
    if (embB) {
        unsigned short* o = embB + (size_t)node * N_INP;
        ushort4 p0, p1;
        p0.x = f2bf(v0.x); p0.y = f2bf(v0.y); p0.z = f2bf(v0.z); p0.w = f2bf(v0.w);
        p1.x = f2bf(v1.x); p1.y = f2bf(v1.y); p1.z = f2bf(v1.z); p1.w = f2bf(v1.w);
        *(ushort4*)(o + c0) = p0;
        *(ushort4*)(o + c1) = p1;
    }
    float d[H];
#pragma unroll
    for (int h = 0; h < H; ++h) {
        const float* uh = su + h * N_INP;
        d[h] = v0.x * uh[c0] + v0.y * uh[c0 + 1] + v0.z * uh[c0 + 2] + v0.w * uh[c0 + 3]
             + v1.x * uh[c1] + v1.y * uh[c1 + 1] + v1.z * uh[c1 + 2] + v1.w * uh[c1 + 3];
#pragma unroll
        for (int off = 32; off >= 1; off >>= 1) d[h] += __shfl_xor(d[h], off, 64);
    }
    if (lane == 0) {
#pragma unroll
        for (int h = 0; h < H; ++h) out[(size_t)node * H + h] = d[h] + ebias[h];
    }
}

__global__ void count_kernel(const int* __restrict__ dst, int* __restrict__ counts, int E) {
    int e = blockIdx.x * blockDim.x + threadIdx.x;
    if (e < E) atomicAdd(&counts[dst[e]], 1);
}

// single-block exclusive scan of counts -> offsets, cursor; offsets[n] = total
__global__ __launch_bounds__(1024) void scan_kernel(const int* __restrict__ counts,
                                                    int* __restrict__ offsets,
                                                    int* __restrict__ cursor, int n) {
    __shared__ int part[1024];
    int t = threadIdx.x;
    const int CH = (n + 1023) / 1024;
    int lo = t * CH, hi = min(lo + CH, n);
    int s = 0;
    for (int i = lo; i < hi; ++i) s += counts[i];
    part[t] = s;
    __syncthreads();
    for (int off = 1; off < 1024; off <<= 1) {
        int v = (t >= off) ? part[t - off] : 0;
        __syncthreads();
        part[t] += v;
        __syncthreads();
    }
    int base = (t == 0) ? 0 : part[t - 1];
    for (int i = lo; i < hi; ++i) {
        offsets[i] = base; cursor[i] = base;
        base += counts[i];
    }
    if (t == 1023) offsets[n] = part[1023];
}

__global__ void scatter_kernel(const int* __restrict__ src, const int* __restrict__ dst,
                               int* __restrict__ cursor, int* __restrict__ csr_src, int E) {
    int e = blockIdx.x * blockDim.x + threadIdx.x;
    if (e < E) {
        int slot = atomicAdd(&cursor[dst[e]], 1);
        csr_src[slot] = src[e];
    }
}

// one wave per dst node: edge softmax over its incoming edges (3 heads)
__global__ __launch_bounds__(256) void alpha_kernel(
    const int* __restrict__ offsets, const int* __restrict__ csr_src,
    const float* __restrict__ el, const float* __restrict__ er,
    float* __restrict__ alpha, int nd) {
    int wave = threadIdx.x >> 6;
    int lane = threadIdx.x & 63;
    int d = blockIdx.x * 4 + wave;
    if (d >= nd) return;
    int lo = offsets[d], hi = offsets[d + 1];
    if (lo == hi) return;
    float er0 = er[(size_t)d * H + 0], er1 = er[(size_t)d * H + 1], er2 = er[(size_t)d * H + 2];
    float m0 = -3.4e38f, m1 = -3.4e38f, m2 = -3.4e38f;
    for (int s = lo + lane; s < hi; s += 64) {
        int u = csr_src[s];
        float e0 = el[(size_t)u * H + 0] + er0; e0 = e0 >= 0.f ? e0 : 0.2f * e0;
        float e1 = el[(size_t)u * H + 1] + er1; e1 = e1 >= 0.f ? e1 : 0.2f * e1;
        float e2 = el[(size_t)u * H + 2] + er2; e2 = e2 >= 0.f ? e2 : 0.2f * e2;
        m0 = fmaxf(m0, e0); m1 = fmaxf(m1, e1); m2 = fmaxf(m2, e2);
    }
#pragma unroll
    for (int off = 32; off >= 1; off >>= 1) {
        m0 = fmaxf(m0, __shfl_xor(m0, off, 64));
        m1 = fmaxf(m1, __shfl_xor(m1, off, 64));
        m2 = fmaxf(m2, __shfl_xor(m2, off, 64));
    }
    float s0 = 0.f, s1 = 0.f, s2 = 0.f;
    for (int s = lo + lane; s < hi; s += 64) {
        int u = csr_src[s];
        float e0 = el[(size_t)u * H + 0] + er0; e0 = e0 >= 0.f ? e0 : 0.2f * e0;
        float e1 = el[(size_t)u * H + 1] + er1; e1 = e1 >= 0.f ? e1 : 0.2f * e1;
        float e2 = el[(size_t)u * H + 2] + er2; e2 = e2 >= 0.f ? e2 : 0.2f * e2;
        float a0 = expf(e0 - m0), a1 = expf(e1 - m1), a2 = expf(e2 - m2);
        alpha[(size_t)s * H + 0] = a0; alpha[(size_t)s * H + 1] = a1; alpha[(size_t)s * H + 2] = a2;
        s0 += a0; s1 += a1; s2 += a2;
    }
#pragma unroll
    for (int off = 32; off >= 1; off >>= 1) {
        s0 += __shfl_xor(s0, off, 64);
        s1 += __shfl_xor(s1, off, 64);
        s2 += __shfl_xor(s2, off, 64);
    }
    float i0 = 1.f / s0, i1 = 1.f / s1, i2 = 1.f / s2;
    for (int s = lo + lane; s < hi; s += 64) {
        alpha[(size_t)s * H + 0] *= i0;
        alpha[(size_t)s * H + 1] *= i1;
        alpha[(size_t)s * H + 2] *= i2;
    }
}

// one block (256 threads) per dst: aggB[d, h*HSTR + c] = sum_e alpha[e,h]*embB[src_e, c]
// aggB[d, h*HSTR + 512] = (deg>0) ? 1 : 0 ; cols [513,HSTR) and [3*HSTR,KP) zero pad.
// Edge indices + alpha triplets are LDS-staged in 512-edge chunks (removes the
// csr/alpha loads from the per-edge critical path); the embB gather loop is
// unrolled x4 with the 4 independent dword loads batched before the FMAs.
#define AGG_CH 512
__global__ __launch_bounds__(256) void agg_kernel(
    const int* __restrict__ offsets, const int* __restrict__ csr_src,
    const float* __restrict__ alpha, const unsigned short* __restrict__ embB,
    unsigned short* __restrict__ aggB, int nd) {
    __shared__ int su[AGG_CH];
    __shared__ float sw0[AGG_CH], sw1[AGG_CH], sw2[AGG_CH];
    int d = blockIdx.x;
    if (d >= nd) return;
    int tid = threadIdx.x;
    int lo = offsets[d], hi = offsets[d + 1];
    const unsigned* ebdw = (const unsigned*)embB;   // 256 dwords per row
    float a00 = 0.f, a01 = 0.f, a10 = 0.f, a11 = 0.f, a20 = 0.f, a21 = 0.f;
    for (int base = lo; base < hi; base += AGG_CH) {
        int cnt = min(hi - base, AGG_CH);
        for (int i = tid; i < cnt; i += 256) {
            int s = base + i;
            su[i] = csr_src[s];
            sw0[i] = alpha[(size_t)s * H + 0];
            sw1[i] = alpha[(size_t)s * H + 1];
            sw2[i] = alpha[(size_t)s * H + 2];
        }
        __syncthreads();
        int i = 0;
        for (; i + 4 <= cnt; i += 4) {
            int u0 = su[i], u1 = su[i + 1], u2 = su[i + 2], u3 = su[i + 3];
            unsigned v0 = ebdw[((size_t)u0 << 8) + tid];
            unsigned v1 = ebdw[((size_t)u1 << 8) + tid];
            unsigned v2 = ebdw[((size_t)u2 << 8) + tid];
            unsigned v3 = ebdw[((size_t)u3 << 8) + tid];
            float w00 = sw0[i], w01 = sw1[i], w02 = sw2[i];
            float w10 = sw0[i+1], w11 = sw1[i+1], w12 = sw2[i+1];
            float w20 = sw0[i+2], w21 = sw1[i+2], w22 = sw2[i+2];
            float w30 = sw0[i+3], w31 = sw1[i+3], w32 = sw2[i+3];
            float x, y;
            x = bflo2f(v0); y = bfhi2f(v0);
            a00 += w00 * x; a01 += w00 * y; a10 += w01 * x; a11 += w01 * y; a20 += w02 * x; a21 += w02 * y;
            x = bflo2f(v1); y = bfhi2f(v1);
            a00 += w10 * x; a01 += w10 * y; a10 += w11 * x; a11 += w11 * y; a20 += w12 * x; a21 += w12 * y;
            x = bflo2f(v2); y = bfhi2f(v2);
            a00 += w20 * x; a01 += w20 * y; a10 += w21 * x; a11 += w21 * y; a20 += w22 * x; a21 += w22 * y;
            x = bflo2f(v3); y = bfhi2f(v3);
            a00 += w30 * x; a01 += w30 * y; a10 += w31 * x; a11 += w31 * y; a20 += w32 * x; a21 += w32 * y;
        }
        for (; i < cnt; ++i) {
            int u = su[i];
            unsigned v = ebdw[((size_t)u << 8) + tid];
            float w0 = sw0[i], w1 = sw1[i], w2 = sw2[i];
            float x = bflo2f(v), y = bfhi2f(v);
            a00 += w0 * x; a01 += w0 * y;
            a10 += w1 * x; a11 += w1 * y;
            a20 += w2 * x; a21 += w2 * y;
        }
        __syncthreads();
    }
    int c = tid * 2;
    size_t base = (size_t)d * KP;
    *(unsigned*)(aggB + base + 0 * HSTR + c) = (unsigned)f2bf(a00) | ((unsigned)f2bf(a01) << 16);
    *(unsigned*)(aggB + base + 1 * HSTR + c) = (unsigned)f2bf(a10) | ((unsigned)f2bf(a11) << 16);
    *(unsigned*)(aggB + base + 2 * HSTR + c) = (unsigned)f2bf(a20) | ((unsigned)f2bf(a21) << 16);
    if (tid == 0) {
        unsigned short flag = (hi > lo) ? (unsigned short)0x3f80 : (unsigned short)0; // bf16 1.0 / 0.0
#pragma unroll
        for (int h = 0; h < H; ++h) {
            aggB[base + h * HSTR + 512] = flag;
            for (int z = 513; z < HSTR; ++z) aggB[base + h * HSTR + z] = 0;
        }
        aggB[base + 3 * HSTR + 0] = 0;
        aggB[base + 3 * HSTR + 1] = 0;
    }
}

// weight GEMM with MLP + TLP: C[M,256] = A[M,K] @ B[K,256], batched over blockIdx.z.
template <int K>
__global__ __launch_bounds__(256) void wgemm(
    const float* __restrict__ A, int lda, size_t sAz,
    const float* __restrict__ B, int ldb, size_t sBz,
    float* __restrict__ C, int ldc, size_t sCz, int M) {
    A += blockIdx.z * sAz; B += blockIdx.z * sBz; C += blockIdx.z * sCz;
    __shared__ float sA[8 * K];
    __shared__ float red[8 * 256];   // 8 rows x (4 ksub x 64 cols)
    int tid = threadIdx.x;
    int r0 = blockIdx.x * 8;
    int bn = blockIdx.y * 64;
    for (int i = tid; i < 8 * K; i += 256) {
        int r = i / K, k = i % K;
        sA[i] = A[(size_t)(r0 + r) * lda + k];
    }
    __syncthreads();
    int cl = tid & 63, ks = tid >> 6;
    int col = bn + cl;
    const int KC = K / 4;
    float acc[8] = {};
    for (int k0 = ks * KC; k0 < ks * KC + KC; k0 += 8) {
        float b[8];
#pragma unroll
        for (int j = 0; j < 8; ++j) b[j] = B[(size_t)(k0 + j) * ldb + col];
#pragma unroll
        for (int j = 0; j < 8; ++j) {
            float bb = b[j];
#pragma unroll
            for (int i = 0; i < 8; ++i) acc[i] += sA[i * K + k0 + j] * bb;
        }
    }
#pragma unroll
    for (int i = 0; i < 8; ++i) red[i * 256 + ks * 64 + cl] = acc[i];
    __syncthreads();
    for (int t = tid; t < 512; t += 256) {
        int i = t >> 6, c = t & 63;
        float s = red[i * 256 + c] + red[i * 256 + 64 + c]
                + red[i * 256 + 128 + c] + red[i * 256 + 192 + c];
        if (r0 + i < M) C[(size_t)(r0 + i) * ldc + bn + c] = s;
    }
}

// wave-per-output bias rows: idx<768: Mmat[h*513+512, j] = bapi . T_h[:, j]
// idx in [768,1024): bz[j] = gat_bias . Whead[:, j] + bhead[j]
__global__ __launch_bounds__(256) void brow_kernel(
    const float* __restrict__ bapi, const float* __restrict__ T,
    const float* __restrict__ gat_bias, const float* __restrict__ Whead,
    const float* __restrict__ bhead,
    float* __restrict__ Mmat, float* __restrict__ bz) {
    int wave = threadIdx.x >> 6, lane = threadIdx.x & 63;
    int idx = blockIdx.x * 4 + wave;
    if (idx < H * N_OUT) {
        int h = idx / N_OUT, j = idx % N_OUT;
        float s = 0.f;
#pragma unroll
        for (int i = 0; i < N_INP / 64; ++i) {
            int cc = lane + i * 64;
            s += bapi[cc] * T[((size_t)h * N_INP + cc) * N_OUT + j];
        }
#pragma unroll
        for (int off = 32; off >= 1; off >>= 1) s += __shfl_xor(s, off, 64);
        if (lane == 0) Mmat[((size_t)(h * 513 + 512)) * N_OUT + j] = s;
    } else if (idx < H * N_OUT + N_OUT) {
        int j = idx - H * N_OUT;
        float s = 0.f;
#pragma unroll
        for (int i = 0; i < HD / 64; ++i) {
            int f = lane + i * 64;
            s += gat_bias[f] * Whead[(size_t)f * N_OUT + j];
        }
#pragma unroll
        for (int off = 32; off >= 1; off >>= 1) s += __shfl_xor(s, off, 64);
        if (lane == 0) bz[j] = s + bhead[j];
    }
}

// MmatT_bf16[n, k] (K-contiguous, padded): k = h*HSTR + c -> Mmat[h*513+c, n], else 0
__global__ void convT_kernel(const float* __restrict__ Mmat, unsigned short* __restrict__ MmatT) {
    int idx = blockIdx.x * blockDim.x + threadIdx.x;
    if (idx >= N_OUT * KP) return;
    int n = idx / KP, k = idx % KP;
    float v = 0.f;
    if (k < H * HSTR) {
        int h = k / HSTR, c = k % HSTR;
        if (c < 513) v = Mmat[((size_t)(h * 513 + c)) * N_OUT + n];
    }
    MmatT[(size_t)n * KP + k] = f2bf(v);
}

// bf16 MFMA GEMM: C[M,256] = A[M,KP] @ BT[256,KP]^T + bias
// BM=32, BN=256 (full N): A streamed from HBM exactly once, B (0.8 MB) L2-resident.
// Reg-staged double-buffer: global->VGPR loads for tile t+3 issued at iter t,
// ds_write at t+1's slot (compiler emits counted vmcnt for the reg deps ->
// ~2 iters of latency cover), raw s_barrier + lgkmcnt(0) only (no vmcnt drain,
// no atomics). 4 waves: each computes 32 rows x 64 cols (acc[2][4]).
// Grid: M/32 = 625 blocks, LDS 36 KB -> 4 blocks/CU.
__global__ __launch_bounds__(256) void gemm_mfma(
    const unsigned short* __restrict__ A, const unsigned short* __restrict__ BT,
    const float* __restrict__ bias, float* __restrict__ C, int M) {
    __shared__ __align__(16) short As[2][32 * 32];    // 2 x 2 KB
    __shared__ __align__(16) short Bs[2][256 * 32];   // 2 x 16 KB
    int tid = threadIdx.x;
    int wave = tid >> 6, lane = tid & 63;
    int bm = blockIdx.x * 32;
    int wn = wave * 64;
    int quad = lane >> 4, m16 = lane & 15;

    // staging geometry: srow = tid>>2 (0..63), schunk = 16B column group
    int srow = tid >> 2;
    int schunk = (tid & 3) * 8;           // in shorts
    bool doA = (tid < 128);               // waves 0,1 also stage the 32-row A tile
    int arow_l = doA ? srow : 0;          // 0..31
    int arow = bm + arow_l; if (arow >= M) arow = M - 1;
    const unsigned short* Ap  = A + (size_t)arow * KP + schunk;
    const unsigned short* Bp0 = BT + (size_t)(srow      ) * KP + schunk;
    const unsigned short* Bp1 = BT + (size_t)(srow +  64) * KP + schunk;
    const unsigned short* Bp2 = BT + (size_t)(srow + 128) * KP + schunk;
    const unsigned short* Bp3 = BT + (size_t)(srow + 192) * KP + schunk;

    f32x4 acc[2][4] = {};
    short8 a0{}, b00{}, b01{}, b02{}, b03{};   // reg set 0 (even tiles)
    short8 a1{}, b10{}, b11{}, b12{}, b13{};   // reg set 1 (odd tiles)

    auto LD = [&](short8& ra, short8& r0, short8& r1, short8& r2, short8& r3, int k0) {
        if (doA) ra = *(const short8*)(Ap + k0);
        r0 = *(const short8*)(Bp0 + k0);
        r1 = *(const short8*)(Bp1 + k0);
        r2 = *(const short8*)(Bp2 + k0);
        r3 = *(const short8*)(Bp3 + k0);
    };
    auto WR = [&](int buf, short8 ra, short8 r0, short8 r1, short8 r2, short8 r3) {
        if (doA) *(short8*)(&As[buf][arow_l * 32 + schunk]) = ra;
        *(short8*)(&Bs[buf][(srow      ) * 32 + schunk]) = r0;
        *(short8*)(&Bs[buf][(srow +  64) * 32 + schunk]) = r1;
        *(short8*)(&Bs[buf][(srow + 128) * 32 + schunk]) = r2;
        *(short8*)(&Bs[buf][(srow + 192) * 32 + schunk]) = r3;
    };
    auto FENCE = [&]() {
        asm volatile("s_waitcnt lgkmcnt(0)" ::: "memory");
        __builtin_amdgcn_sched_barrier(0);
        __builtin_amdgcn_s_barrier();
        __builtin_amdgcn_sched_barrier(0);
    };

    // prologue: tiles 0,1 loaded; tile 0 written; tile 2 in flight (set 0)
    LD(a0, b00, b01, b02, b03, 0);
    LD(a1, b10, b11, b12, b13, 32);
    WR(0, a0, b00, b01, b02, b03);
    LD(a0, b00, b01, b02, b03, 64);
    FENCE();

    for (int t = 0; t < GEMM_NT; ++t) {
        int rb = t & 1;
        short8 af[2], bf[4];
#pragma unroll
        for (int mt = 0; mt < 2; ++mt)
            af[mt] = *(const short8*)(&As[rb][(mt * 16 + m16) * 32 + quad * 8]);
#pragma unroll
        for (int nt = 0; nt < 4; ++nt)
            bf[nt] = *(const short8*)(&Bs[rb][(wn + nt * 16 + m16) * 32 + quad * 8]);
        // write tile t+1 (held in set (t+1)&1), then refill that set with tile t+3
        int k3 = (t + 3) * 32;
        if (t & 1) {   // t odd -> tile t+1 even -> set 0
            if (t + 1 < GEMM_NT) WR(rb ^ 1, a0, b00, b01, b02, b03);
            if (t + 3 < GEMM_NT) LD(a0, b00, b01, b02, b03, k3);
        } else {       // t even -> tile t+1 odd -> set 1
            if (t + 1 < GEMM_NT) WR(rb ^ 1, a1, b10, b11, b12, b13);
            if (t + 3 < GEMM_NT) LD(a1, b10, b11, b12, b13, k3);
        }
#pragma unroll
        for (int mt = 0; mt < 2; ++mt)
#pragma unroll
            for (int nt = 0; nt < 4; ++nt)
                acc[mt][nt] = __builtin_amdgcn_mfma_f32_16x16x32_bf16(
                    af[mt], bf[nt], acc[mt][nt], 0, 0, 0);
        FENCE();
    }

    float bcol[4];
#pragma unroll
    for (int nt = 0; nt < 4; ++nt) bcol[nt] = bias[wn + nt * 16 + m16];
#pragma unroll
    for (int mt = 0; mt < 2; ++mt) {
#pragma unroll
        for (int i = 0; i < 4; ++i) {
            int r = bm + mt * 16 + quad * 4 + i;
            if (r >= M) continue;
#pragma unroll
            for (int nt = 0; nt < 4; ++nt) {
                int col = wn + nt * 16 + m16;
                C[(size_t)r * N_OUT + col] = acc[mt][nt][i] + bcol[nt];
            }
        }
    }
}

// ---------------------------------------------------------------------------
extern "C" void kernel_launch(void* const* d_in, const int* in_sizes, int n_in,
                              void* d_out, int out_size, void* d_ws, size_t ws_size,
                              hipStream_t stream) {
    const float* emb_api  = (const float*)d_in[0];
    const float* emb_file = (const float*)d_in[1];
    // d_in[2] = e_tensor (unused by the reference)
    const int*   src      = (const int*)d_in[3];
    const int*   dst      = (const int*)d_in[4];
    const float* Wapi     = (const float*)d_in[5];
    const float* bapi     = (const float*)d_in[6];
    const float* Wfile    = (const float*)d_in[7];
    const float* bfile    = (const float*)d_in[8];
    const float* Wsrc     = (const float*)d_in[9];
    const float* Wdst     = (const float*)d_in[10];
    const float* attn_l   = (const float*)d_in[11];
    const float* attn_r   = (const float*)d_in[12];
    const float* gat_bias = (const float*)d_in[13];
    const float* Whead    = (const float*)d_in[14];
    const float* bhead    = (const float*)d_in[15];
    float* out = (float*)d_out;

    const int NAPI = in_sizes[0] / N_INP;   // 50000
    const int NFIL = in_sizes[1] / N_INP;   // 20000
    const int E    = in_sizes[3];           // 250000

    // workspace carve-up
    char* p = (char*)d_ws;
    auto alloc = [&](size_t bytes) -> void* {
        void* r = (void*)p;
        p += (bytes + 255) & ~(size_t)255;
        return r;
    };
    float* el      = (float*)alloc((size_t)NAPI * H * 4);
    float* er      = (float*)alloc((size_t)NFIL * H * 4);
    float* vbuf    = (float*)alloc(2 * H * N_INP * 4);
    float* ubuf    = (float*)alloc(2 * H * N_INP * 4);
    float* ebias   = (float*)alloc(8 * 4);
    float* T       = (float*)alloc((size_t)H * N_INP * N_OUT * 4);
    float* Mmat    = (float*)alloc((size_t)AGG_D * N_OUT * 4);
    float* bz      = (float*)alloc(N_OUT * 4);
    int*   counts  = (int*)alloc((size_t)NFIL * 4);
    int*   offsets = (int*)alloc((size_t)(NFIL + 1) * 4);
    int*   cursor  = (int*)alloc((size_t)NFIL * 4);
    int*   csr_src = (int*)alloc((size_t)E * 4);
    float* alphaB  = (float*)alloc((size_t)E * H * 4);
    unsigned short* embB  = (unsigned short*)alloc((size_t)NAPI * N_INP * 2);
    unsigned short* aggB  = (unsigned short*)alloc((size_t)NFIL * KP * 2);
    unsigned short* MmatT = (unsigned short*)alloc((size_t)N_OUT * KP * 2);
    (void)ws_size; (void)n_in; (void)out_size;

    // --- weight precompute (tiny, parallelism-first) ---
    v_kernel<<<(2 * H * N_INP + 3) / 4, 256, 0, stream>>>(Wsrc, Wdst, attn_l, attn_r, vbuf);
    u_kernel<<<(2 * H * N_INP + 6 + 3) / 4, 256, 0, stream>>>(Wapi, Wfile, bapi, bfile, vbuf, ubuf, ebias);
    // T_h = Wsrc[:, h*256:(h+1)*256] @ Whead[h*256:(h+1)*256, :]  (batched over h)
    wgemm<N_OUT><<<dim3(N_INP / 8, 4, H), 256, 0, stream>>>(
        Wsrc, HD, (size_t)N_OUT,
        Whead, N_OUT, (size_t)N_OUT * N_OUT,
        T, N_OUT, (size_t)N_INP * N_OUT, N_INP);
    // Mmat rows [h*513 .. h*513+511] = Wapi @ T_h  (batched over h)
    wgemm<N_INP><<<dim3(N_INP / 8, 4, H), 256, 0, stream>>>(
        Wapi, N_INP, (size_t)0,
        T, N_OUT, (size_t)N_INP * N_OUT,
        Mmat, N_OUT, (size_t)513 * N_OUT, N_INP);
    brow_kernel<<<(H * N_OUT + N_OUT + 3) / 4, 256, 0, stream>>>(
        bapi, T, gat_bias, Whead, bhead, Mmat, bz);
    convT_kernel<<<(N_OUT * KP + 255) / 256, 256, 0, stream>>>(Mmat, MmatT);

    // --- attention logits (+ bf16 copy of emb_api) ---
    elr_kernel<<<(NAPI + 3) / 4, 256, 0, stream>>>(emb_api, ubuf, ebias, el, embB, NAPI);
    elr_kernel<<<(NFIL + 3) / 4, 256, 0, stream>>>(emb_file, ubuf + H * N_INP, ebias + 3, er, nullptr, NFIL);

    // --- CSR build (by dst) ---
    zero_int_kernel<<<(NFIL + 255) / 256, 256, 0, stream>>>(counts, NFIL);
    count_kernel<<<(E + 255) / 256, 256, 0, stream>>>(dst, counts, E);
    scan_kernel<<<1, 1024, 0, stream>>>(counts, offsets, cursor, NFIL);
    scatter_kernel<<<(E + 255) / 256, 256, 0, stream>>>(src, dst, cursor, csr_src, E);

    // --- edge softmax + aggregation (bf16 out) ---
    alpha_kernel<<<(NFIL + 3) / 4, 256, 0, stream>>>(offsets, csr_src, el, er, alphaB, NFIL);
    agg_kernel<<<NFIL, 256, 0, stream>>>(offsets, csr_src, alphaB, embB, aggB, NFIL);

    // --- final fused GEMM (bf16 MFMA): out = aggB @ MmatT^T + bz ---
    gemm_mfma<<<dim3((NFIL + 31) / 32), 256, 0, stream>>>(
        aggB, MmatT, bz, out, NFIL);
}